// Round 1
// baseline (229.649 us; speedup 1.0000x reference)
//
#include <hip/hip_runtime.h>
#include <math.h>

// Problem dims (fixed by reference)
constexpr int B_ = 128, T_ = 512, I_ = 1024, H_ = 2048, O_ = 512;
#define BETA 0.9f

// ws float layout: w[512] | y[B*I] | Z[B*H]
constexpr int WOFF = 0;
constexpr int YOFF = 512;
constexpr int ZOFF = YOFF + B_ * I_;
constexpr int WS_FLOATS = ZOFF + B_ * H_;

constexpr int TCH = 64;  // timesteps per wreduce block

// ---------------------------------------------------------------------------
// Kernel 1: init weights w[t], zero y, Z = Wsum*b_in, out = T*b_out
// ---------------------------------------------------------------------------
__global__ __launch_bounds__(256) void init_kernel(float* __restrict__ ws,
                                                   const float* __restrict__ b_in,
                                                   const float* __restrict__ b_out,
                                                   float* __restrict__ out, float wsum) {
    int idx = blockIdx.x * 256 + threadIdx.x;
    const int total = WS_FLOATS + B_ * O_;
    if (idx >= total) return;
    if (idx < 512) {
        // w[t] = (1 - beta^(T-t)) / (1 - beta)
        ws[idx] = (1.0f - powf(BETA, (float)(T_ - idx))) * (1.0f / (1.0f - BETA));
    } else if (idx < ZOFF) {
        ws[idx] = 0.0f;                       // y accumulator
    } else if (idx < WS_FLOATS) {
        int j = idx - ZOFF;
        ws[idx] = wsum * b_in[j & (H_ - 1)];  // Z bias init
    } else {
        int j = idx - WS_FLOATS;
        out[j] = (float)T_ * b_out[j & (O_ - 1)];  // out bias init
    }
}

// ---------------------------------------------------------------------------
// Kernel 2: y[b,i] += sum_{t in chunk} w[t] * x[b,t,i]   (streaming, float4)
// grid = B * (T/TCH), block = 256 (each thread: 4 consecutive i)
// ---------------------------------------------------------------------------
__global__ __launch_bounds__(256) void wreduce_kernel(const float* __restrict__ x,
                                                      float* __restrict__ ws) {
    const float* w = ws + WOFF;
    float* y = ws + YOFF;
    int b  = blockIdx.x >> 3;   // T/TCH = 8 chunks
    int tc = blockIdx.x & 7;
    int t0 = tc * TCH;
    int i  = threadIdx.x * 4;
    const float* xp = x + (size_t)b * T_ * I_ + (size_t)t0 * I_ + i;
    float4 acc = {0.f, 0.f, 0.f, 0.f};
#pragma unroll 8
    for (int t = 0; t < TCH; ++t) {
        float wt = w[t0 + t];
        float4 v = *(const float4*)(xp + (size_t)t * I_);
        acc.x += wt * v.x; acc.y += wt * v.y; acc.z += wt * v.z; acc.w += wt * v.w;
    }
    float* yp = y + b * I_ + i;
    atomicAdd(yp + 0, acc.x);
    atomicAdd(yp + 1, acc.y);
    atomicAdd(yp + 2, acc.z);
    atomicAdd(yp + 3, acc.w);
}

// ---------------------------------------------------------------------------
// Kernel 3/4: split-K f32 GEMM, C += A[M,K] @ B[K,N], atomicAdd epilogue.
// Fixed geometry: BM=64, BN=128, BK=16, TM=4, TN=8, 256 threads.
// grid = (N/BN, M/BM, K/KCH)
// ---------------------------------------------------------------------------
template <int BM, int BN, int BK, int TM, int TN, int KCH>
__global__ __launch_bounds__(256) void gemm_splitk(const float* __restrict__ A,
                                                   const float* __restrict__ Bm,
                                                   float* __restrict__ C,
                                                   int M, int N, int K) {
    static_assert(BM == 64 && BN == 128 && BK == 16 && TM == 4 && TN == 8, "fixed geometry");
    __shared__ float As[BK][BM + 1];
    __shared__ float Bs[BK][BN];
    const int n0 = blockIdx.x * BN;
    const int m0 = blockIdx.y * BM;
    const int kbase = blockIdx.z * KCH;
    const int tid = threadIdx.x;
    const int row = tid >> 4;   // 0..15 -> M
    const int col = tid & 15;   // 0..15 -> N

    float acc[TM][TN] = {};

    for (int k0 = 0; k0 < KCH; k0 += BK) {
        // A tile: 64x16, one float4 per thread (coalesced along K)
        {
            int m  = tid >> 2;
            int kk = (tid & 3) * 4;
            float4 v = *(const float4*)(A + (size_t)(m0 + m) * K + kbase + k0 + kk);
            As[kk + 0][m] = v.x; As[kk + 1][m] = v.y;
            As[kk + 2][m] = v.z; As[kk + 3][m] = v.w;
        }
        // B tile: 16x128, two float4 per thread (coalesced along N)
        {
            int kk = tid >> 5;          // 0..7
            int nf = (tid & 31) * 4;    // 0..124
            *(float4*)&Bs[kk][nf]     = *(const float4*)(Bm + (size_t)(kbase + k0 + kk) * N + n0 + nf);
            *(float4*)&Bs[kk + 8][nf] = *(const float4*)(Bm + (size_t)(kbase + k0 + kk + 8) * N + n0 + nf);
        }
        __syncthreads();
#pragma unroll
        for (int kk = 0; kk < BK; ++kk) {
            float a[TM], bb[TN];
#pragma unroll
            for (int i = 0; i < TM; ++i) a[i] = As[kk][row * TM + i];
#pragma unroll
            for (int j = 0; j < TN; ++j) bb[j] = Bs[kk][col * TN + j];
#pragma unroll
            for (int i = 0; i < TM; ++i)
#pragma unroll
                for (int j = 0; j < TN; ++j) acc[i][j] += a[i] * bb[j];
        }
        __syncthreads();
    }
#pragma unroll
    for (int i = 0; i < TM; ++i)
#pragma unroll
        for (int j = 0; j < TN; ++j)
            atomicAdd(&C[(size_t)(m0 + row * TM + i) * N + n0 + col * TN + j], acc[i][j]);
}

// ---------------------------------------------------------------------------
extern "C" void kernel_launch(void* const* d_in, const int* in_sizes, int n_in,
                              void* d_out, int out_size, void* d_ws, size_t ws_size,
                              hipStream_t stream) {
    const float* x     = (const float*)d_in[0];
    const float* W_in  = (const float*)d_in[1];
    const float* b_in  = (const float*)d_in[2];
    const float* W_out = (const float*)d_in[3];
    const float* b_out = (const float*)d_in[4];
    float* out = (float*)d_out;
    float* ws  = (float*)d_ws;

    // Wsum = sum_t w_t, computed exactly in double on host
    const double beta = 0.9;
    const double bT = pow(beta, (double)T_);
    const float wsum = (float)(((double)T_ - beta * (1.0 - bT) / (1.0 - beta)) / (1.0 - beta));

    const int total = WS_FLOATS + B_ * O_;
    init_kernel<<<(total + 255) / 256, 256, 0, stream>>>(ws, b_in, b_out, out, wsum);

    wreduce_kernel<<<B_ * (T_ / TCH), 256, 0, stream>>>(x, ws);

    // Z = y @ W_in (+bias already in Z)
    gemm_splitk<64, 128, 16, 4, 8, 128>
        <<<dim3(H_ / 128, B_ / 64, I_ / 128), 256, 0, stream>>>(ws + YOFF, W_in, ws + ZOFF, B_, H_, I_);

    // out = Z @ W_out (+bias already in out)
    gemm_splitk<64, 128, 16, 4, 8, 128>
        <<<dim3(O_ / 128, B_ / 64, H_ / 128), 256, 0, stream>>>(ws + ZOFF, W_out, out, B_, O_, H_);
}

// Round 3
// 86.056 us; speedup vs baseline: 2.6686x; 2.6686x over previous
//
#include <hip/hip_runtime.h>
#include <hip/hip_bf16.h>
#include <math.h>

// Problem dims (fixed by reference)
constexpr int B_ = 128, T_ = 512, I_ = 1024, H_ = 2048, O_ = 512;
#define BETA 0.9f

// ws float layout: w[512] | y[B*I] | Z[B*H]
constexpr int WOFF = 0;
constexpr int YOFF = 512;
constexpr int ZOFF = YOFF + B_ * I_;
constexpr int WS_FLOATS = ZOFF + B_ * H_;

typedef __attribute__((ext_vector_type(4))) short short4v;   // 4 bf16 = 2 VGPR
typedef __attribute__((ext_vector_type(4))) float float4v;   // 4 f32  = 4 VGPR

__device__ inline void mfma16(float4v& acc, short4v a, short4v b) {
    // D = A*B + C, classic CDNA 16x16x16 bf16 layout:
    //   A: row=l&15, k=4*(l>>4)+j ; B: col=l&15, same k ; D: col=l&15, row=4*(l>>4)+i
    asm("v_mfma_f32_16x16x16_bf16 %0, %1, %2, %0" : "+v"(acc) : "v"(a), "v"(b));
}

// ---------------------------------------------------------------------------
// Kernel 1: init w[t], zero y, Z = Wsum*b_in, out = T*b_out
// ---------------------------------------------------------------------------
__global__ __launch_bounds__(256) void init_kernel(float* __restrict__ ws,
                                                   const float* __restrict__ b_in,
                                                   const float* __restrict__ b_out,
                                                   float* __restrict__ out, float wsum) {
    int idx = blockIdx.x * 256 + threadIdx.x;
    const int total = WS_FLOATS + B_ * O_;
    if (idx >= total) return;
    if (idx < 512) {
        ws[idx] = (1.0f - powf(BETA, (float)(T_ - idx))) * (1.0f / (1.0f - BETA));
    } else if (idx < ZOFF) {
        ws[idx] = 0.0f;                       // y accumulator
    } else if (idx < WS_FLOATS) {
        int j = idx - ZOFF;
        ws[idx] = wsum * b_in[j & (H_ - 1)];  // Z bias init
    } else {
        int j = idx - WS_FLOATS;
        out[j] = (float)T_ * b_out[j & (O_ - 1)];  // out bias init
    }
}

// ---------------------------------------------------------------------------
// Kernel 2: y[b,i] += sum_{t in chunk} w[t] * x[b,t,i]
// grid = B * (T/32) = 2048 blocks, 256 threads, thread -> float4 of I.
// 8-deep explicit load batching; nontemporal (x is stream-once).
// ---------------------------------------------------------------------------
constexpr int TCH = 32;
__global__ __launch_bounds__(256) void wreduce_kernel(const float* __restrict__ x,
                                                      float* __restrict__ ws) {
    __shared__ float wl[TCH];
    const int b  = blockIdx.x >> 4;   // T/TCH = 16 chunks
    const int tc = blockIdx.x & 15;
    const int t0 = tc * TCH;
    if (threadIdx.x < TCH) wl[threadIdx.x] = ws[WOFF + t0 + threadIdx.x];
    __syncthreads();

    const int i = threadIdx.x * 4;
    const float* xp = x + (size_t)b * T_ * I_ + (size_t)t0 * I_ + i;
    float4v acc = {0.f, 0.f, 0.f, 0.f};
#pragma unroll
    for (int tb = 0; tb < TCH; tb += 8) {
        float4v v[8];
#pragma unroll
        for (int j = 0; j < 8; ++j)
            v[j] = __builtin_nontemporal_load((const float4v*)(xp + (size_t)(tb + j) * I_));
#pragma unroll
        for (int j = 0; j < 8; ++j) {
            const float wt = wl[tb + j];
            acc.x += wt * v[j].x; acc.y += wt * v[j].y;
            acc.z += wt * v[j].z; acc.w += wt * v[j].w;
        }
    }
    float* yp = ws + YOFF + b * I_ + i;
    atomicAdd(yp + 0, acc.x);
    atomicAdd(yp + 1, acc.y);
    atomicAdd(yp + 2, acc.z);
    atomicAdd(yp + 3, acc.w);
}

// ---------------------------------------------------------------------------
// Kernel 3/4: C[128,N] += A[128,K] @ B[K,N], bf16 MFMA, f32 atomic epilogue.
// Block: 256 thr = 4 waves; BM=128 (full M), BN=64, BK=32, split-K by KCH.
// A,B are f32 in memory; converted to bf16 during LDS staging.
// grid = (N/64, K/KCH)
// ---------------------------------------------------------------------------
template <int KGLOB, int NGLOB, int KCH>
__global__ __launch_bounds__(256) void mm128(const float* __restrict__ A,
                                             const float* __restrict__ Bm,
                                             float* __restrict__ C) {
    constexpr int BN = 64, BK = 32, PAD = 8;
    __shared__ __hip_bfloat16 As[128][BK + PAD];  // [row][k]
    __shared__ __hip_bfloat16 Bs[BN][BK + PAD];   // transposed: [n][k]

    const int n0    = blockIdx.x * BN;
    const int kbase = blockIdx.y * KCH;
    const int tid   = threadIdx.x;
    const int lane  = tid & 63;
    const int w     = tid >> 6;       // wave id 0..3 -> rows [w*32, w*32+32)
    const int lo    = lane & 15;
    const int hi    = lane >> 4;

    float4v acc[2][4];
#pragma unroll
    for (int mf = 0; mf < 2; ++mf)
#pragma unroll
        for (int nf = 0; nf < 4; ++nf) acc[mf][nf] = (float4v){0.f, 0.f, 0.f, 0.f};

    for (int k0 = kbase; k0 < kbase + KCH; k0 += BK) {
        // --- stage A tile 128x32: thread -> row=tid>>1, half-k=(tid&1)*16
        {
            const int row = tid >> 1;
            const int kh  = (tid & 1) * 16;
            const float* ap = A + (size_t)row * KGLOB + k0 + kh;
#pragma unroll
            for (int j = 0; j < 4; ++j) {
                float4 v = *(const float4*)(ap + 4 * j);
                union { short4v s; __hip_bfloat16 h[4]; } u;
                u.h[0] = __float2bfloat16(v.x); u.h[1] = __float2bfloat16(v.y);
                u.h[2] = __float2bfloat16(v.z); u.h[3] = __float2bfloat16(v.w);
                *(short4v*)&As[row][kh + 4 * j] = u.s;
            }
        }
        // --- stage B tile 32x64 transposed: thread -> k=tid>>3, n-chunk=(tid&7)*8
        {
            const int k  = tid >> 3;
            const int nq = (tid & 7) * 8;
            const float* bp = Bm + (size_t)(k0 + k) * NGLOB + n0 + nq;
#pragma unroll
            for (int j = 0; j < 2; ++j) {
                float4 v = *(const float4*)(bp + 4 * j);
                Bs[nq + 4 * j + 0][k] = __float2bfloat16(v.x);
                Bs[nq + 4 * j + 1][k] = __float2bfloat16(v.y);
                Bs[nq + 4 * j + 2][k] = __float2bfloat16(v.z);
                Bs[nq + 4 * j + 3][k] = __float2bfloat16(v.w);
            }
        }
        __syncthreads();
#pragma unroll
        for (int ks = 0; ks < 2; ++ks) {
            const int kk = ks * 16 + 4 * hi;
            short4v a[2], bf[4];
#pragma unroll
            for (int mf = 0; mf < 2; ++mf)
                a[mf] = *(const short4v*)&As[w * 32 + mf * 16 + lo][kk];
#pragma unroll
            for (int nf = 0; nf < 4; ++nf)
                bf[nf] = *(const short4v*)&Bs[nf * 16 + lo][kk];
#pragma unroll
            for (int mf = 0; mf < 2; ++mf)
#pragma unroll
                for (int nf = 0; nf < 4; ++nf) mfma16(acc[mf][nf], a[mf], bf[nf]);
        }
        __syncthreads();
    }
    // --- epilogue: split-K atomic accumulate (C pre-initialized with bias)
#pragma unroll
    for (int mf = 0; mf < 2; ++mf)
#pragma unroll
        for (int nf = 0; nf < 4; ++nf)
#pragma unroll
            for (int i = 0; i < 4; ++i) {
                const int row = w * 32 + mf * 16 + hi * 4 + i;
                const int col = n0 + nf * 16 + lo;
                atomicAdd(&C[(size_t)row * NGLOB + col], acc[mf][nf][i]);
            }
}

// ---------------------------------------------------------------------------
extern "C" void kernel_launch(void* const* d_in, const int* in_sizes, int n_in,
                              void* d_out, int out_size, void* d_ws, size_t ws_size,
                              hipStream_t stream) {
    const float* x     = (const float*)d_in[0];
    const float* W_in  = (const float*)d_in[1];
    const float* b_in  = (const float*)d_in[2];
    const float* W_out = (const float*)d_in[3];
    const float* b_out = (const float*)d_in[4];
    float* out = (float*)d_out;
    float* ws  = (float*)d_ws;

    // Wsum = sum_t (1-beta^(T-t))/(1-beta), exact in double on host
    const double beta = 0.9;
    const double bT = pow(beta, (double)T_);
    const float wsum = (float)(((double)T_ - beta * (1.0 - bT) / (1.0 - beta)) / (1.0 - beta));

    const int total = WS_FLOATS + B_ * O_;
    init_kernel<<<(total + 255) / 256, 256, 0, stream>>>(ws, b_in, b_out, out, wsum);

    wreduce_kernel<<<B_ * (T_ / TCH), 256, 0, stream>>>(x, ws);

    // Z = y @ W_in  (bias pre-loaded) : K=1024, N=2048, split-K 4 -> 128 blocks
    mm128<I_, H_, 256><<<dim3(H_ / 64, I_ / 256), 256, 0, stream>>>(ws + YOFF, W_in, ws + ZOFF);

    // out = Z @ W_out (bias pre-loaded) : K=2048, N=512, split-K 8 -> 64 blocks
    mm128<H_, O_, 256><<<dim3(O_ / 64, H_ / 256), 256, 0, stream>>>(ws + ZOFF, W_out, out);
}